// Round 4
// baseline (1503.341 us; speedup 1.0000x reference)
//
#include <hip/hip_runtime.h>
#include <hip/hip_cooperative_groups.h>

namespace cg = cooperative_groups;

#define BATCH 16
#define GRID 1024
#define BLOCK 256
#define STRIDE (GRID * BLOCK)

struct KArgs {
  const float* in[40];
  float* out;
  float* ws;
};

// ---------------- d-stage: 4-lane groups, lane j owns vec[j] -----------------
template <int H, int NH>
__device__ __forceinline__ void d_stage(const float* __restrict__ xin,
                                        float* __restrict__ xout,
                                        const float* __restrict__ A,
                                        const float* __restrict__ v,
                                        const float* __restrict__ w, int g0) {
  const int total = NH * NH * 64;
  for (int g = g0; g < total; g += STRIDE) {
    int j = g & 3;
    int b = (g >> 2) & 15;
    int p = g >> 6;
    int pi = p / NH, pj = p % NH;
    const float* xb = xin + b * H * H;
    float* yb = xout + b * H * H;
    int r0 = 1 + 2 * pi, c0 = 1 + 2 * pj;
    float t[4];
    t[0] = xb[r0 * H + c0];
    t[1] = xb[r0 * H + c0 + 1];
    t[2] = xb[(r0 + 1) * H + c0];
    t[3] = xb[(r0 + 1) * H + c0 + 1];
    const float* Ap = A + p * 128;  // [s][f][4][4]
    float vec = v[p * 4 + j];
#pragma unroll
    for (int s = 0; s < 4; s++) {
      const float* A0 = Ap + s * 32;
      float p0 = 0.0f, p1 = 0.0f;
#pragma unroll
      for (int i = 0; i < 4; i++) {
        float sv = __shfl(vec, i, 4);
        p0 = fmaf(sv, A0[i * 4 + j], p0);
        p1 = fmaf(sv, A0[16 + i * 4 + j], p1);
      }
      vec = t[s] * p0 + (1.0f - t[s]) * p1;
    }
    float acc = 0.0f;
#pragma unroll
    for (int i = 0; i < 4; i++)
      acc += __shfl(vec, i, 4) * w[p * 16 + i * 4 + j];
    acc = fmaxf(acc, 0.0f);
    // in-place safe: all t-loads precede stores in wave program order
    yb[(r0 + (j >> 1)) * H + (c0 + (j & 1))] = acc;
  }
}

// ---------------- i-stage: 16-lane groups, lane j owns vec[j] ----------------
template <int H>
__device__ __forceinline__ void i_stage(const float* __restrict__ xin,
                                        float* __restrict__ hn,
                                        const float* __restrict__ A,
                                        const float* __restrict__ v,
                                        const float* __restrict__ w, int g0) {
  const int W2 = H / 2;
  const int total = W2 * W2 * 256;
  for (int g = g0; g < total; g += STRIDE) {
    int j = g & 15;
    int b = (g >> 4) & 15;
    int p = g >> 8;
    int pi = p / W2, pj = p % W2;
    const float* xb = xin + b * H * H;
    int r0 = 2 * pi, c0 = 2 * pj;
    float t[4];
    t[0] = xb[r0 * H + c0];
    t[1] = xb[r0 * H + c0 + 1];
    t[2] = xb[(r0 + 1) * H + c0];
    t[3] = xb[(r0 + 1) * H + c0 + 1];
    const float* Ap = A + p * 2048;  // [s][f][16][16]
    float vec = v[p * 16 + j];
#pragma unroll
    for (int s = 0; s < 4; s++) {
      const float* A0 = Ap + s * 512;
      float p0 = 0.0f, p1 = 0.0f;
#pragma unroll
      for (int i = 0; i < 16; i++) {
        float sv = __shfl(vec, i, 16);
        p0 = fmaf(sv, A0[i * 16 + j], p0);
        p1 = fmaf(sv, A0[256 + i * 16 + j], p1);
      }
      vec = t[s] * p0 + (1.0f - t[s]) * p1;
    }
    float partial = vec * w[p * 16 + j];
#pragma unroll
    for (int off = 8; off >= 1; off >>= 1)
      partial += __shfl_xor(partial, off, 16);
    if (j == 0) hn[b * W2 * W2 + p] = fmaxf(partial, 0.0f);
  }
}

// ---------------- cooperative mega-kernel ------------------------------------
__global__ __launch_bounds__(BLOCK, 4) void mega_kernel(KArgs a) {
  cg::grid_group grid = cg::this_grid();
  const int g0 = blockIdx.x * BLOCK + threadIdx.x;
  float* h0 = a.ws;            // 16*128*128 = 262144
  float* h1 = h0 + 262144;     // 16*64*64
  float* h2 = h1 + 65536;      // 16*32*32
  float* h3 = h2 + 16384;      // 16*16*16
  float* h4 = h3 + 4096;       // 16*8*8
  float* h5 = h4 + 1024;       // 16*4*4
  float* h6 = h5 + 256;        // 16*2*2
  const float* x = a.in[0];

  // stage 1: copy border cells x -> h0, and d1 (reads x, writes h0 interior)
  for (int g = g0; g < 16 * 512; g += STRIDE) {
    int b = g >> 9, k = g & 511;
    if (k < 508) {
      int r, c;
      if (k < 128)      { r = 0;           c = k; }
      else if (k < 256) { r = 127;         c = k - 128; }
      else if (k < 382) { r = k - 256 + 1; c = 0; }
      else              { r = k - 382 + 1; c = 127; }
      h0[b * 16384 + r * 128 + c] = x[b * 16384 + r * 128 + c];
    }
  }
  d_stage<128, 63>(x, h0, a.in[1], a.in[2], a.in[3], g0);
  grid.sync();
  i_stage<128>(h0, h1, a.in[4], a.in[5], a.in[6], g0);
  grid.sync();
  d_stage<64, 31>(h1, h1, a.in[7], a.in[8], a.in[9], g0);
  grid.sync();
  i_stage<64>(h1, h2, a.in[10], a.in[11], a.in[12], g0);
  grid.sync();
  d_stage<32, 15>(h2, h2, a.in[13], a.in[14], a.in[15], g0);
  grid.sync();
  i_stage<32>(h2, h3, a.in[16], a.in[17], a.in[18], g0);
  grid.sync();
  d_stage<16, 7>(h3, h3, a.in[19], a.in[20], a.in[21], g0);
  grid.sync();
  i_stage<16>(h3, h4, a.in[22], a.in[23], a.in[24], g0);
  grid.sync();
  d_stage<8, 3>(h4, h4, a.in[25], a.in[26], a.in[27], g0);
  grid.sync();
  i_stage<8>(h4, h5, a.in[28], a.in[29], a.in[30], g0);
  grid.sync();
  d_stage<4, 1>(h5, h5, a.in[31], a.in[32], a.in[33], g0);
  grid.sync();
  i_stage<4>(h5, h6, a.in[34], a.in[35], a.in[36], g0);
  grid.sync();

  // final head: 256 threads (16 b-units x 16 j-lanes), block 0 only
  if (g0 < 256) {
    int j = g0 & 15, b = g0 >> 4;
    const float* fA = a.in[37];
    const float* fv = a.in[38];
    const float* fw = a.in[39];
    float t[4];
#pragma unroll
    for (int s = 0; s < 4; s++) t[s] = h6[b * 4 + s];
    float vec = fv[j];
#pragma unroll
    for (int s = 0; s < 4; s++) {
      const float* A0 = fA + s * 512;
      float p0 = 0.0f, p1 = 0.0f;
#pragma unroll
      for (int i = 0; i < 16; i++) {
        float sv = __shfl(vec, i, 16);
        p0 = fmaf(sv, A0[i * 16 + j], p0);
        p1 = fmaf(sv, A0[256 + i * 16 + j], p1);
      }
      vec = t[s] * p0 + (1.0f - t[s]) * p1;
    }
    // out[b, o] = relu(sum_i vec_i * fw[i*10+o]); all 16 lanes run the shfls
    float acc = 0.0f;
#pragma unroll
    for (int i = 0; i < 16; i++) {
      float sv = __shfl(vec, i, 16);
      float wv = (j < 10) ? fw[i * 10 + j] : 0.0f;
      acc = fmaf(sv, wv, acc);
    }
    if (j < 10) a.out[b * 10 + j] = fmaxf(acc, 0.0f);
  }
}

// ================= fallback path (R3 kernels, runtime H) =====================
__global__ __launch_bounds__(256) void d_kernel_j(
    float* __restrict__ h, const float* __restrict__ A,
    const float* __restrict__ v, const float* __restrict__ w,
    int H, int nh) {
  int g = blockIdx.x * blockDim.x + threadIdx.x;
  int total = nh * nh * BATCH * 4;
  if (g >= total) return;
  int j = g & 3;
  int b = (g >> 2) & 15;
  int p = g >> 6;
  int pi = p / nh, pj = p % nh;
  float* xb = h + (size_t)b * H * H;
  int r0 = 1 + 2 * pi, c0 = 1 + 2 * pj;
  float t[4];
  t[0] = xb[r0 * H + c0];
  t[1] = xb[r0 * H + c0 + 1];
  t[2] = xb[(r0 + 1) * H + c0];
  t[3] = xb[(r0 + 1) * H + c0 + 1];
  const float* Ap = A + (size_t)p * 128;
  float vec = v[p * 4 + j];
#pragma unroll
  for (int s = 0; s < 4; s++) {
    const float* A0 = Ap + s * 32;
    float p0 = 0.0f, p1 = 0.0f;
#pragma unroll
    for (int i = 0; i < 4; i++) {
      float sv = __shfl(vec, i, 4);
      p0 = fmaf(sv, A0[i * 4 + j], p0);
      p1 = fmaf(sv, A0[16 + i * 4 + j], p1);
    }
    vec = t[s] * p0 + (1.0f - t[s]) * p1;
  }
  float acc = 0.0f;
#pragma unroll
  for (int i = 0; i < 4; i++) acc += __shfl(vec, i, 4) * w[p * 16 + i * 4 + j];
  xb[(r0 + (j >> 1)) * H + (c0 + (j & 1))] = fmaxf(acc, 0.0f);
}

__global__ __launch_bounds__(256) void i_kernel_j(
    const float* __restrict__ h, float* __restrict__ hn,
    const float* __restrict__ A, const float* __restrict__ v,
    const float* __restrict__ w, int H) {
  int W2 = H >> 1;
  int g = blockIdx.x * blockDim.x + threadIdx.x;
  int j = g & 15;
  int b = (g >> 4) & 15;
  int p = g >> 8;
  const float* xb = h + (size_t)b * H * H;
  int pi = p / W2, pj = p % W2;
  int r0 = 2 * pi, c0 = 2 * pj;
  float t[4];
  t[0] = xb[r0 * H + c0];
  t[1] = xb[r0 * H + c0 + 1];
  t[2] = xb[(r0 + 1) * H + c0];
  t[3] = xb[(r0 + 1) * H + c0 + 1];
  const float* Ap = A + (size_t)p * 2048;
  float vec = v[p * 16 + j];
#pragma unroll
  for (int s = 0; s < 4; s++) {
    const float* A0 = Ap + s * 512;
    float p0 = 0.0f, p1 = 0.0f;
#pragma unroll
    for (int i = 0; i < 16; i++) {
      float sv = __shfl(vec, i, 16);
      p0 = fmaf(sv, A0[i * 16 + j], p0);
      p1 = fmaf(sv, A0[256 + i * 16 + j], p1);
    }
    vec = t[s] * p0 + (1.0f - t[s]) * p1;
  }
  float partial = vec * w[p * 16 + j];
#pragma unroll
  for (int off = 8; off >= 1; off >>= 1)
    partial += __shfl_xor(partial, off, 16);
  if (j == 0) hn[(size_t)b * W2 * W2 + p] = fmaxf(partial, 0.0f);
}

__global__ void final_kernel(const float* __restrict__ h6,
                             const float* __restrict__ A,
                             const float* __restrict__ v,
                             const float* __restrict__ w,
                             float* __restrict__ out) {
  int g0 = threadIdx.x;
  if (g0 >= 256) return;
  int j = g0 & 15, b = g0 >> 4;
  float t[4];
#pragma unroll
  for (int s = 0; s < 4; s++) t[s] = h6[b * 4 + s];
  float vec = v[j];
#pragma unroll
  for (int s = 0; s < 4; s++) {
    const float* A0 = A + s * 512;
    float p0 = 0.0f, p1 = 0.0f;
#pragma unroll
    for (int i = 0; i < 16; i++) {
      float sv = __shfl(vec, i, 16);
      p0 = fmaf(sv, A0[i * 16 + j], p0);
      p1 = fmaf(sv, A0[256 + i * 16 + j], p1);
    }
    vec = t[s] * p0 + (1.0f - t[s]) * p1;
  }
  float acc = 0.0f;
#pragma unroll
  for (int i = 0; i < 16; i++) {
    float sv = __shfl(vec, i, 16);
    float wv = (j < 10) ? w[i * 10 + j] : 0.0f;
    acc = fmaf(sv, wv, acc);
  }
  if (j < 10) out[b * 10 + j] = fmaxf(acc, 0.0f);
}

extern "C" void kernel_launch(void* const* d_in, const int* in_sizes, int n_in,
                              void* d_out, int out_size, void* d_ws, size_t ws_size,
                              hipStream_t stream) {
  KArgs ha;
  for (int i = 0; i < 40; i++) ha.in[i] = (const float*)d_in[i];
  ha.out = (float*)d_out;
  ha.ws = (float*)d_ws;

  void* params[] = {(void*)&ha};
  hipError_t err = hipLaunchCooperativeKernel((const void*)mega_kernel,
                                              dim3(GRID), dim3(BLOCK), params,
                                              0, stream);
  if (err == hipSuccess) return;

  // ---- fallback: R3 multi-launch path ----
  const float* x = (const float*)d_in[0];
  float* ws = (float*)d_ws;
  hipMemcpyAsync(ws, x, (size_t)BATCH * 128 * 128 * sizeof(float),
                 hipMemcpyDeviceToDevice, stream);
  int H = 128;
  size_t hoff = 0;
  for (int l = 0; l < 6; l++) {
    const float* dA = (const float*)d_in[1 + 6 * l + 0];
    const float* dv = (const float*)d_in[1 + 6 * l + 1];
    const float* dw = (const float*)d_in[1 + 6 * l + 2];
    const float* iA = (const float*)d_in[1 + 6 * l + 3];
    const float* iv = (const float*)d_in[1 + 6 * l + 4];
    const float* iw = (const float*)d_in[1 + 6 * l + 5];
    int nh = (H - 2) / 2;
    int totd = nh * nh * BATCH * 4;
    d_kernel_j<<<(totd + 255) / 256, 256, 0, stream>>>(ws + hoff, dA, dv, dw, H, nh);
    int W2 = H / 2;
    size_t hoff_next = hoff + (size_t)BATCH * H * H;
    int toti = W2 * W2 * BATCH * 16;
    i_kernel_j<<<toti / 256, 256, 0, stream>>>(ws + hoff, ws + hoff_next, iA, iv, iw, H);
    hoff = hoff_next;
    H = W2;
  }
  final_kernel<<<1, 256, 0, stream>>>(ws + hoff, (const float*)d_in[37],
                                      (const float*)d_in[38],
                                      (const float*)d_in[39], (float*)d_out);
}

// Round 5
// 216.774 us; speedup vs baseline: 6.9351x; 6.9351x over previous
//
#include <hip/hip_runtime.h>

#define BATCH 16

// ---------------------------------------------------------------------------
// Fused d+i unit: one 16-lane group computes one i-patch output, recomputing
// the d-transform of its 4 input cells on the fly (4 lanes per cell).
// Lane layout: j = sg*4 + j4; sg = which of the 4 i-patch cells, j4 = d-lane.
// ---------------------------------------------------------------------------
template <int H>
__device__ __forceinline__ float fused_di_unit(
    const float* __restrict__ xb,  // one image, H*H (global or LDS)
    int p, int j,
    const float* __restrict__ dA, const float* __restrict__ dv,
    const float* __restrict__ dw,
    const float* __restrict__ iA, const float* __restrict__ iv,
    const float* __restrict__ iw) {
  constexpr int NH = (H - 2) / 2;
  constexpr int W2 = H / 2;
  int pi = p / W2, pj = p % W2;
  int sg = j >> 2, j4 = j & 3;
  int r = 2 * pi + (sg >> 1), c = 2 * pj + (sg & 1);
  float tcell;
  bool border = (r == 0) | (r == H - 1) | (c == 0) | (c == H - 1);
  if (border) {
    tcell = xb[r * H + c];  // border cells pass through untouched by d
  } else {
    int dpi = (r - 1) >> 1, dpj = (c - 1) >> 1;
    int sd = ((r - 1) & 1) * 2 + ((c - 1) & 1);
    int dp = dpi * NH + dpj;
    int R0 = 1 + 2 * dpi, C0 = 1 + 2 * dpj;
    // lane j4 loads cell j4 of the d-patch
    float tin = xb[(R0 + (j4 >> 1)) * H + (C0 + (j4 & 1))];
    const float* Ap = dA + dp * 128;  // [s][f][4][4]
    float vec = dv[dp * 4 + j4];
#pragma unroll
    for (int s = 0; s < 4; s++) {
      float ts = __shfl(tin, s, 4);
      const float* A0 = Ap + s * 32;
      float q0 = 0.f, q1 = 0.f;
#pragma unroll
      for (int i = 0; i < 4; i++) {
        float sv = __shfl(vec, i, 4);
        q0 = fmaf(sv, A0[i * 4 + j4], q0);
        q1 = fmaf(sv, A0[16 + i * 4 + j4], q1);
      }
      vec = ts * q0 + (1.0f - ts) * q1;
    }
    float y = 0.f;
#pragma unroll
    for (int i = 0; i < 4; i++)
      y = fmaf(__shfl(vec, i, 4), dw[dp * 16 + i * 4 + j4], y);
    y = fmaxf(y, 0.0f);
    tcell = __shfl(y, sd, 4);  // the d-output cell this i-cell needs
  }
  // broadcast the 4 cell values to all 16 lanes
  float t[4];
  t[0] = __shfl(tcell, 0, 16);
  t[1] = __shfl(tcell, 4, 16);
  t[2] = __shfl(tcell, 8, 16);
  t[3] = __shfl(tcell, 12, 16);
  // i-MPS (D=16), lane j owns component j
  const float* Ap = iA + p * 2048;  // [s][f][16][16]
  float vec = iv[p * 16 + j];
#pragma unroll
  for (int s = 0; s < 4; s++) {
    const float* A0 = Ap + s * 512;
    float q0 = 0.f, q1 = 0.f;
#pragma unroll
    for (int i = 0; i < 16; i++) {
      float sv = __shfl(vec, i, 16);
      q0 = fmaf(sv, A0[i * 16 + j], q0);
      q1 = fmaf(sv, A0[256 + i * 16 + j], q1);
    }
    vec = t[s] * q0 + (1.0f - t[s]) * q1;
  }
  float partial = vec * iw[p * 16 + j];
#pragma unroll
  for (int off = 8; off >= 1; off >>= 1)
    partial += __shfl_xor(partial, off, 16);
  return fmaxf(partial, 0.0f);
}

// ---------------------------------------------------------------------------
// One fused level: grid = W2*W2 blocks x 256 threads; unit = (p, b), 16 lanes.
// ---------------------------------------------------------------------------
template <int H>
__global__ __launch_bounds__(256) void level_kernel(
    const float* __restrict__ xin, float* __restrict__ hn,
    const float* __restrict__ dA, const float* __restrict__ dv,
    const float* __restrict__ dw, const float* __restrict__ iA,
    const float* __restrict__ iv, const float* __restrict__ iw) {
  constexpr int W2 = H / 2;
  int g = blockIdx.x * 256 + threadIdx.x;
  int j = g & 15;
  int b = (g >> 4) & 15;
  int p = g >> 8;
  const float* xb = xin + b * H * H;
  float o = fused_di_unit<H>(xb, p, j, dA, dv, dw, iA, iv, iw);
  if (j == 0) hn[b * W2 * W2 + p] = o;
}

// ---------------------------------------------------------------------------
// Tail: levels 4-6 + final head. One workgroup per batch element (16 WGs);
// whole sub-pyramid lives in LDS; params are shared across WGs (L2 broadcast).
// ---------------------------------------------------------------------------
struct TailArgs {
  const float* h3;
  const float* in[21];  // d4A..fw  (d_in[19..39])
  float* out;
};

__global__ __launch_bounds__(1024) void tail_kernel(TailArgs a) {
  __shared__ float x4[256];  // 16x16
  __shared__ float h4[64];   // 8x8
  __shared__ float h5[16];   // 4x4
  __shared__ float h6[4];    // 2x2
  int b = blockIdx.x;
  int tid = threadIdx.x;
  if (tid < 256) x4[tid] = a.h3[b * 256 + tid];
  __syncthreads();
  // level 4: H=16 -> 64 units * 16 lanes = 1024 threads
  {
    int j = tid & 15, p = tid >> 4;
    float o = fused_di_unit<16>(x4, p, j, a.in[0], a.in[1], a.in[2],
                                a.in[3], a.in[4], a.in[5]);
    if (j == 0) h4[p] = o;
  }
  __syncthreads();
  // level 5: H=8 -> 16 units -> 256 threads
  if (tid < 256) {
    int j = tid & 15, p = tid >> 4;
    float o = fused_di_unit<8>(h4, p, j, a.in[6], a.in[7], a.in[8],
                               a.in[9], a.in[10], a.in[11]);
    if (j == 0) h5[p] = o;
  }
  __syncthreads();
  // level 6: H=4 -> 4 units -> 64 threads
  if (tid < 64) {
    int j = tid & 15, p = tid >> 4;
    float o = fused_di_unit<4>(h5, p, j, a.in[12], a.in[13], a.in[14],
                               a.in[15], a.in[16], a.in[17]);
    if (j == 0) h6[p] = o;
  }
  __syncthreads();
  // final head: flat (2x2) -> 10 classes; 16 lanes, lane j owns vec[j]
  if (tid < 16) {
    int j = tid;
    const float* fA = a.in[18];
    const float* fv = a.in[19];
    const float* fw = a.in[20];
    float t[4] = {h6[0], h6[1], h6[2], h6[3]};
    float vec = fv[j];
#pragma unroll
    for (int s = 0; s < 4; s++) {
      const float* A0 = fA + s * 512;
      float q0 = 0.f, q1 = 0.f;
#pragma unroll
      for (int i = 0; i < 16; i++) {
        float sv = __shfl(vec, i, 16);
        q0 = fmaf(sv, A0[i * 16 + j], q0);
        q1 = fmaf(sv, A0[256 + i * 16 + j], q1);
      }
      vec = t[s] * q0 + (1.0f - t[s]) * q1;
    }
    float acc = 0.0f;
#pragma unroll
    for (int i = 0; i < 16; i++) {
      float sv = __shfl(vec, i, 16);
      float wv = (j < 10) ? fw[i * 10 + j] : 0.0f;
      acc = fmaf(sv, wv, acc);
    }
    if (j < 10) a.out[b * 10 + j] = fmaxf(acc, 0.0f);
  }
}

extern "C" void kernel_launch(void* const* d_in, const int* in_sizes, int n_in,
                              void* d_out, int out_size, void* d_ws, size_t ws_size,
                              hipStream_t stream) {
  const float* x = (const float*)d_in[0];
  float* ws = (float*)d_ws;
  float* h1 = ws;            // 16*64*64 = 65536
  float* h2 = h1 + 65536;    // 16*32*32 = 16384
  float* h3 = h2 + 16384;    // 16*16*16 = 4096

  // level 1: reads x directly (borders pass through inside the fused unit)
  level_kernel<128><<<64 * 64, 256, 0, stream>>>(
      x, h1, (const float*)d_in[1], (const float*)d_in[2],
      (const float*)d_in[3], (const float*)d_in[4], (const float*)d_in[5],
      (const float*)d_in[6]);
  level_kernel<64><<<32 * 32, 256, 0, stream>>>(
      h1, h2, (const float*)d_in[7], (const float*)d_in[8],
      (const float*)d_in[9], (const float*)d_in[10], (const float*)d_in[11],
      (const float*)d_in[12]);
  level_kernel<32><<<16 * 16, 256, 0, stream>>>(
      h2, h3, (const float*)d_in[13], (const float*)d_in[14],
      (const float*)d_in[15], (const float*)d_in[16], (const float*)d_in[17],
      (const float*)d_in[18]);

  TailArgs ta;
  ta.h3 = h3;
  for (int i = 0; i < 21; i++) ta.in[i] = (const float*)d_in[19 + i];
  ta.out = (float*)d_out;
  tail_kernel<<<BATCH, 1024, 0, stream>>>(ta);
}